// Round 5
// baseline (1064.565 us; speedup 1.0000x reference)
//
#include <hip/hip_runtime.h>
#include <hip/hip_bf16.h>
#include <math.h>

// Problem constants (from reference setup_inputs)
#define Bq   16
#define Sq   1024
#define Hq   1024
#define Oq   256
#define Lq   4
#define NHq  8
#define DHq  128
#define Mq   (Bq*Sq)      // 16384 rows
#define HHq  (Hq*Hq)      // 1048576
#define NCc  32           // scan chunks
#define CTc  32           // timesteps per chunk

typedef __bf16 bf16x8 __attribute__((ext_vector_type(8)));
typedef float  f32x4  __attribute__((ext_vector_type(4)));

__device__ __forceinline__ float bf2f(unsigned int u) {
    union { unsigned int i; float f; } x; x.i = u << 16; return x.f;
}
__device__ __forceinline__ unsigned short f2bf(float f) {
    union { float f; unsigned int i; } x; x.f = f;
    unsigned int r = x.i + 0x7fffu + ((x.i >> 16) & 1u);   // RNE
    return (unsigned short)(r >> 16);
}
__device__ __forceinline__ float sigm(float x) { return 1.f / (1.f + __expf(-x)); }

// ---------------- fp32 -> bf16 convert ----------------
__global__ void cvt_kernel(const float* __restrict__ src, unsigned short* __restrict__ dst, int n) {
    int i = blockIdx.x * 256 + threadIdx.x;
    if (i < n) dst[i] = f2bf(src[i]);
}

// ---------------- fused weight convert: Wcat[l][f;i;h][H][H] ----------------
__global__ void cvtW_kernel(const float* __restrict__ Wf, const float* __restrict__ Wi,
                            const float* __restrict__ Wh, unsigned short* __restrict__ Wcat) {
    int i = blockIdx.x * 256 + threadIdx.x;     // L*3*HH
    int l = (i >> 20) / 3;
    int r = i - l * 3 * HHq;
    int g = r >> 20; int j = r & (HHq - 1);
    const float* s = (g == 0) ? Wf : (g == 1) ? Wi : Wh;
    Wcat[i] = f2bf(s[(size_t)l * HHq + j]);
}

// ---------------- assemble per-layer [bf;bi;bh] bias (L x 3072) ----------------
__global__ void bias3_kernel(const float* __restrict__ bf_, const float* __restrict__ bi_,
                             const float* __restrict__ bh_, float* __restrict__ out) {
    int i = blockIdx.x * 256 + threadIdx.x;          // L*3H = 12288
    int l = i / (3*Hq); int r = i % (3*Hq); int g = r >> 10; int j = r & (Hq-1);
    const float* s = (g == 0) ? bf_ : (g == 1) ? bi_ : bh_;
    out[i] = s[l*Hq + j];
}

// ---------------- bf16 GEMM: C[M,N] = A[M,K] * W[N,K]^T + bias (bf16 out) ----------------
// 128x128 tile, BK=32, DOUBLE-BUFFERED LDS (2x16KB), ONE barrier per K-iter:
// stage buf[i+1] before computing buf[i], so the compiler's vmcnt(0)-before-barrier
// drain lands AFTER the MFMA phase (R4 post-mortem: old structure paid full load
// latency per iter -> barrier-latency-bound at ~3000 cyc/iter vs 155 MFMA cyc).
// Staging/fragment swizzle = R2's proven zero-conflict mapping.
// XCD-aware 1D dispatch: xcd=lid&7 gets 16 contiguous bm rows, bn-fast -> A-tile
// L2-resident across its 24 consumers, W L3-resident.
__device__ __forceinline__ void gl2lds16(const unsigned short* g, unsigned short* l) {
    __builtin_amdgcn_global_load_lds((const __attribute__((address_space(1))) void*)g,
                                     (__attribute__((address_space(3))) void*)l, 16, 0, 0);
}

__global__ __launch_bounds__(256)
void gemm_bt_kernel(const unsigned short* __restrict__ A, const unsigned short* __restrict__ W,
                    const float* __restrict__ bias, unsigned short* __restrict__ C,
                    int N, int K, int nbn)
{
    __shared__ unsigned short As[2*4096];
    __shared__ unsigned short Ws[2*4096];
    const int tid  = threadIdx.x;

    // XCD swizzle: nbm = Mq/128 = 128 rows of blocks; 16 bm-rows per XCD.
    const int lid = blockIdx.x;
    const int xcd = lid & 7;
    const int s   = lid >> 3;
    const int bm  = xcd * 16 + s / nbn;
    const int bn  = s % nbn;

    const int wid  = tid >> 6, lane = tid & 63;
    const int wm   = (wid >> 1) * 64, wn = (wid & 1) * 64;
    const int l15  = lane & 15, quad = lane >> 4;

    const unsigned short* Ag = A + (size_t)(bm*128) * K;
    const unsigned short* Wg = W + (size_t)(bn*128) * K;

    // staging (R2 mapping): wave w rows [w*32,w*32+32), lane l -> row r0=(w*32)+(l>>2)
    // (+16 for 2nd issue), phys chunk l&3 holding global chunk (l&3)^((r0>>1)&3).
    const int r0   = wid*32 + (lane >> 2);
    const int cst  = (lane & 3) ^ ((r0 >> 1) & 3);
    const size_t g0 = (size_t)r0 * K + cst*8;
    const size_t g1 = (size_t)(r0 + 16) * K + cst*8;
    const int lofs0 = wid*1024;          // elements into buffer
    const int lofs1 = wid*1024 + 512;

    // fragment read swizzle (R2): phys chunk = quad ^ ((l15>>1)&3)
    const int crd = quad ^ ((l15 >> 1) & 3);

    f32x4 acc[4][4] = {};

    const int niter = K >> 5;            // 32

    // prologue: stage buf0
    gl2lds16(Ag + g0, &As[lofs0]);
    gl2lds16(Ag + g1, &As[lofs1]);
    gl2lds16(Wg + g0, &Ws[lofs0]);
    gl2lds16(Wg + g1, &Ws[lofs1]);
    __syncthreads();                     // vmcnt(0) drain: buf0 visible to all

    for (int it = 0; it < niter; ++it) {
        const int cur = it & 1;
        if (it + 1 < niter) {            // stage next buffer (drained at loop-end barrier)
            const int nxt = (it + 1) & 1;
            const size_t k1 = (size_t)(it + 1) << 5;
            gl2lds16(Ag + g0 + k1, &As[nxt*4096 + lofs0]);
            gl2lds16(Ag + g1 + k1, &As[nxt*4096 + lofs1]);
            gl2lds16(Wg + g0 + k1, &Ws[nxt*4096 + lofs0]);
            gl2lds16(Wg + g1 + k1, &Ws[nxt*4096 + lofs1]);
        }
        bf16x8 af[4], wf[4];
        #pragma unroll
        for (int t = 0; t < 4; ++t) {
            af[t] = *(const bf16x8*)&As[cur*4096 + (wm + t*16 + l15)*32 + crd*8];
            wf[t] = *(const bf16x8*)&Ws[cur*4096 + (wn + t*16 + l15)*32 + crd*8];
        }
        #pragma unroll
        for (int tm = 0; tm < 4; ++tm)
            #pragma unroll
            for (int tn = 0; tn < 4; ++tn)
                acc[tm][tn] = __builtin_amdgcn_mfma_f32_16x16x32_bf16(af[tm], wf[tn], acc[tm][tn], 0, 0, 0);
        __syncthreads();                 // one barrier/iter: reads of cur done + my next-stage drained
    }

    // epilogue: C[row=quad*4+r][col=l15] per 16x16 tile (verified m89/m91 layout)
    #pragma unroll
    for (int tm = 0; tm < 4; ++tm) {
        int row0 = bm*128 + wm + tm*16 + quad*4;
        #pragma unroll
        for (int tn = 0; tn < 4; ++tn) {
            int col = bn*128 + wn + tn*16 + l15;
            float bv = bias[col];
            #pragma unroll
            for (int r = 0; r < 4; ++r)
                C[(size_t)(row0 + r) * N + col] = f2bf(acc[tm][tn][r] + bv);
        }
    }
}

// ---------------- fused gate + chunked scan ----------------
// Pass A: per (b,chunk,j-pair): P = prod fp, Aagg = local scan from h=0. 1024 blocks.
__global__ __launch_bounds__(256)
void scan_sum_kernel(const unsigned short* __restrict__ G,
                     float* __restrict__ Ps, float* __restrict__ Asum) {
    int bid = blockIdx.x;                    // B*NC*2 = 1024
    int tid = threadIdx.x;
    int b = bid >> 6; int r = bid & 63; int chunk = r >> 1; int jb = r & 1;
    int j = jb*512 + tid*2;
    size_t base = ((size_t)(b*Sq + chunk*CTc)) * 3072 + j;
    float P0 = 1.f, P1 = 1.f, A0 = 0.f, A1 = 0.f;
    for (int s = 0; s < CTc; ++s) {
        size_t ro = base + (size_t)s * 3072;
        unsigned int uf = *(const unsigned int*)(G + ro);
        unsigned int ui = *(const unsigned int*)(G + ro + 1024);
        unsigned int uh = *(const unsigned int*)(G + ro + 2048);
        float f0 = sigm(bf2f(uf & 0xffffu)), f1 = sigm(bf2f(uf >> 16));
        float i0 = sigm(bf2f(ui & 0xffffu)), i1 = sigm(bf2f(ui >> 16));
        float h0 = bf2f(uh & 0xffffu),       h1 = bf2f(uh >> 16);
        float rd0 = 1.f / (f0 + i0),         rd1 = 1.f / (f1 + i1);
        float fp0 = f0 * rd0,                fp1 = f1 * rd1;
        float ad0 = i0 * rd0 * h0,           ad1 = i1 * rd1 * h1;
        P0 *= fp0; A0 = fp0 * A0 + ad0;
        P1 *= fp1; A1 = fp1 * A1 + ad1;
    }
    int oi = (b*NCc + chunk)*Hq + j;
    Ps[oi] = P0; Ps[oi+1] = P1;
    Asum[oi] = A0; Asum[oi+1] = A1;
}

// Pass B: chunk-level prefix. h entering chunk c stored to Hb.
__global__ void scan_base_kernel(const float* __restrict__ Ps, const float* __restrict__ Asum,
                                 float* __restrict__ Hb) {
    int t = blockIdx.x * 256 + threadIdx.x;  // B*H = 16384
    int b = t >> 10, j = t & 1023;
    float h = 0.f;
    for (int c = 0; c < NCc; ++c) {
        int idx = (b*NCc + c)*Hq + j;
        Hb[idx] = h;
        h = Ps[idx] * h + Asum[idx];
    }
}

// Pass C: recompute gates, scan with correct init, write bf16 h.
__global__ __launch_bounds__(256)
void scan_out_kernel(const unsigned short* __restrict__ G, const float* __restrict__ Hb,
                     unsigned short* __restrict__ Ho) {
    int bid = blockIdx.x;                    // B*NC*2 = 1024
    int tid = threadIdx.x;
    int b = bid >> 6; int r = bid & 63; int chunk = r >> 1; int jb = r & 1;
    int j = jb*512 + tid*2;
    size_t base = ((size_t)(b*Sq + chunk*CTc)) * 3072 + j;
    int oi = (b*NCc + chunk)*Hq + j;
    float h0 = Hb[oi], h1 = Hb[oi+1];
    for (int s = 0; s < CTc; ++s) {
        size_t ro = base + (size_t)s * 3072;
        unsigned int uf = *(const unsigned int*)(G + ro);
        unsigned int ui = *(const unsigned int*)(G + ro + 1024);
        unsigned int uh = *(const unsigned int*)(G + ro + 2048);
        float f0 = sigm(bf2f(uf & 0xffffu)), f1 = sigm(bf2f(uf >> 16));
        float i0 = sigm(bf2f(ui & 0xffffu)), i1 = sigm(bf2f(ui >> 16));
        float g0 = bf2f(uh & 0xffffu),       g1 = bf2f(uh >> 16);
        float rd0 = 1.f / (f0 + i0),         rd1 = 1.f / (f1 + i1);
        h0 = f0 * rd0 * h0 + i0 * rd0 * g0;
        h1 = f1 * rd1 * h1 + i1 * rd1 * g1;
        unsigned int packed = (unsigned int)f2bf(h0) | ((unsigned int)f2bf(h1) << 16);
        *(unsigned int*)(Ho + (size_t)(b*Sq + chunk*CTc + s) * Hq + j) = packed;
    }
}

// ---------------- extract last-position activations as fp32 ----------------
__global__ void xlast_kernel(const unsigned short* __restrict__ act, float* __restrict__ xl) {
    int i = blockIdx.x * 256 + threadIdx.x;  // B*H
    int b = i >> 10, j = i & 1023;
    xl[i] = bf2f((unsigned int)act[((size_t)(b*Sq + Sq-1)) * Hq + j]);
}

// ---------------- wave-per-row GEMV: out[b,n] = W[n,:].x[b,:] + bias[n] (+resid[b,n]) ----------------
__global__ __launch_bounds__(256)
void gemv_kernel(const float* __restrict__ W, const float* __restrict__ xv,
                 const float* __restrict__ bias, const float* __restrict__ resid,
                 float* __restrict__ out, int N) {
    int b = blockIdx.x;
    int w = threadIdx.x >> 6, lane = threadIdx.x & 63;
    int n = blockIdx.y*4 + w;
    __shared__ float xs[Hq];
    *(float4*)&xs[threadIdx.x*4] = *(const float4*)&xv[(size_t)b*Hq + threadIdx.x*4];
    __syncthreads();
    const float4* wr = (const float4*)(W + (size_t)n * Hq);
    float a = 0.f;
    #pragma unroll
    for (int c = 0; c < 4; ++c) {
        float4 wv = wr[c*64 + lane];
        float4 x4 = *(const float4*)&xs[c*256 + lane*4];
        a += wv.x*x4.x + wv.y*x4.y + wv.z*x4.z + wv.w*x4.w;
    }
    #pragma unroll
    for (int st = 32; st > 0; st >>= 1) a += __shfl_xor(a, st, 64);
    if (lane == 0) out[(size_t)b*N + n] = a + bias[n] + (resid ? resid[(size_t)b*Hq + n] : 0.f);
}

// ---------------- attention for the single last-position query ----------------
// 128 blocks x 1024 threads. Score: 16 lanes/row (coalesced uint4 + shfl-xor16).
// PV: 16-way S-split with packed b32 V loads, LDS combine.
__global__ __launch_bounds__(1024)
void attn_kernel(const unsigned short* __restrict__ KV,
                 const float* __restrict__ q, float* __restrict__ o) {
    int b = blockIdx.x >> 3, nh = blockIdx.x & 7;
    int tid = threadIdx.x;
    __shared__ float qs[DHq];
    __shared__ float p[Sq];
    __shared__ float redw[16];
    __shared__ float red2[16*DHq];
    if (tid < DHq) qs[tid] = q[b*Hq + nh*DHq + tid] * 0.08838834764831845f;  // fold 1/sqrt(128)
    __syncthreads();

    const int g = tid >> 4, l = tid & 15;
    const unsigned short* Kb = KV + (size_t)b*Sq*2048 + nh*DHq;
    float lmax = -1e30f;
    #pragma unroll 4
    for (int it = 0; it < 16; ++it) {
        int s = it*64 + g;
        union { uint4 v; unsigned short u[8]; } kk;
        kk.v = *(const uint4*)(Kb + (size_t)s*2048 + l*8);
        float a = 0.f;
        #pragma unroll
        for (int j = 0; j < 8; ++j) a += bf2f((unsigned int)kk.u[j]) * qs[l*8 + j];
        a += __shfl_xor(a, 1, 16);
        a += __shfl_xor(a, 2, 16);
        a += __shfl_xor(a, 4, 16);
        a += __shfl_xor(a, 8, 16);
        if (l == 0) p[s] = a;
        lmax = fmaxf(lmax, a);
    }
    #pragma unroll
    for (int st = 32; st > 0; st >>= 1) lmax = fmaxf(lmax, __shfl_xor(lmax, st, 64));
    if ((tid & 63) == 0) redw[tid >> 6] = lmax;
    __syncthreads();
    float mx = redw[0];
    #pragma unroll
    for (int i = 1; i < 16; ++i) mx = fmaxf(mx, redw[i]);

    float e = __expf(p[tid] - mx);
    float ls = e;
    #pragma unroll
    for (int st = 32; st > 0; st >>= 1) ls += __shfl_xor(ls, st, 64);
    __syncthreads();              // everyone done reading redw(max) and p(raw)
    p[tid] = e;
    if ((tid & 63) == 0) redw[tid >> 6] = ls;
    __syncthreads();
    float ssum = 0.f;
    #pragma unroll
    for (int i = 0; i < 16; ++i) ssum += redw[i];
    float inv = 1.f / ssum;

    // PV: thread -> (sb = s-block of 64, d2 = col pair)
    int d2 = (tid & 63) * 2, sb = tid >> 6;
    const unsigned short* Vb = KV + (size_t)b*Sq*2048 + 1024 + nh*DHq + d2;
    float a0 = 0.f, a1 = 0.f;
    for (int s = sb*64; s < sb*64 + 64; ++s) {
        unsigned int vv = *(const unsigned int*)(Vb + (size_t)s*2048);
        float pw = p[s];
        a0 += pw * bf2f(vv & 0xffffu);
        a1 += pw * bf2f(vv >> 16);
    }
    red2[sb*DHq + d2] = a0;
    red2[sb*DHq + d2 + 1] = a1;
    __syncthreads();
    if (tid < DHq) {
        float a = 0.f;
        #pragma unroll
        for (int i = 0; i < 16; ++i) a += red2[i*DHq + tid];
        o[b*Hq + nh*DHq + tid] = a * inv;
    }
}

extern "C" void kernel_launch(void* const* d_in, const int* in_sizes, int n_in,
                              void* d_out, int out_size, void* d_ws, size_t ws_size,
                              hipStream_t stream) {
    const float* x        = (const float*)d_in[0];
    const float* Wf       = (const float*)d_in[1];
    const float* bfv      = (const float*)d_in[2];
    const float* Wi       = (const float*)d_in[3];
    const float* biv      = (const float*)d_in[4];
    const float* Wh       = (const float*)d_in[5];
    const float* bhv      = (const float*)d_in[6];
    const float* in_proj_w= (const float*)d_in[7];
    const float* in_proj_b= (const float*)d_in[8];
    const float* out_w    = (const float*)d_in[9];
    const float* out_b    = (const float*)d_in[10];
    const float* fc_w     = (const float*)d_in[11];
    const float* fc_b     = (const float*)d_in[12];
    float* outp = (float*)d_out;

    // workspace carve (~196 MB)
    char* p = (char*)d_ws;
    auto alloc = [&](size_t bytes) -> void* {
        void* r = (void*)p; p += (bytes + 255) & ~(size_t)255; return r;
    };
    unsigned short* Wcat = (unsigned short*)alloc((size_t)Lq*3*HHq*2);  // 24 MB
    unsigned short* Wkv  = (unsigned short*)alloc((size_t)2048*Hq*2);   //  4 MB
    float*          Bias3= (float*)alloc((size_t)Lq*3*Hq*4);            // 48 KB
    unsigned short* actA = (unsigned short*)alloc((size_t)Mq*Hq*2);     // 32 MB
    unsigned short* actB = (unsigned short*)alloc((size_t)Mq*Hq*2);     // 32 MB
    unsigned short* Gpre = (unsigned short*)alloc((size_t)Mq*3*Hq*2);   // 96 MB
    float* Ps   = (float*)alloc((size_t)Bq*NCc*Hq*4);                   //  2 MB
    float* Asum = (float*)alloc((size_t)Bq*NCc*Hq*4);                   //  2 MB
    float* Hb   = (float*)alloc((size_t)Bq*NCc*Hq*4);                   //  2 MB
    unsigned short* KV = Gpre;                                          // alias (post-layers)
    float* xl   = (float*)alloc((size_t)Bq*Hq*4);
    float* qbuf = (float*)alloc((size_t)Bq*Hq*4);
    float* obuf = (float*)alloc((size_t)Bq*Hq*4);
    float* rbuf = (float*)alloc((size_t)Bq*Hq*4);

    // --- conversions ---
    cvt_kernel<<<Mq*Hq/256, 256, 0, stream>>>(x, actA, Mq*Hq);
    cvtW_kernel<<<Lq*3*HHq/256, 256, 0, stream>>>(Wf, Wi, Wh, Wcat);
    cvt_kernel<<<2048*Hq/256, 256, 0, stream>>>(in_proj_w + (size_t)Hq*Hq, Wkv, 2048*Hq);
    bias3_kernel<<<(Lq*3*Hq)/256, 256, 0, stream>>>(bfv, biv, bhv, Bias3);

    // --- minLSTM layers ---
    unsigned short* cur = actA;
    unsigned short* nxt = actB;
    for (int l = 0; l < Lq; ++l) {
        gemm_bt_kernel<<<(Mq/128)*(3*Hq/128), 256, 0, stream>>>(
            cur, Wcat + (size_t)l*3*HHq, Bias3 + l*3*Hq, Gpre, 3*Hq, Hq, 3*Hq/128);
        scan_sum_kernel<<<Bq*NCc*2, 256, 0, stream>>>(Gpre, Ps, Asum);
        scan_base_kernel<<<Bq*Hq/256, 256, 0, stream>>>(Ps, Asum, Hb);
        scan_out_kernel<<<Bq*NCc*2, 256, 0, stream>>>(Gpre, Hb, nxt);
        unsigned short* t = cur; cur = nxt; nxt = t;
    }

    // --- attention (only last-position query matters) ---
    gemm_bt_kernel<<<(Mq/128)*(2048/128), 256, 0, stream>>>(
        cur, Wkv, in_proj_b + Hq, KV, 2048, Hq, 2048/128);
    xlast_kernel<<<Bq*Hq/256, 256, 0, stream>>>(cur, xl);
    gemv_kernel<<<dim3(Bq, Hq/4), 256, 0, stream>>>(in_proj_w, xl, in_proj_b, nullptr, qbuf, Hq);
    attn_kernel<<<Bq*NHq, 1024, 0, stream>>>(KV, qbuf, obuf);
    gemv_kernel<<<dim3(Bq, Hq/4), 256, 0, stream>>>(out_w, obuf, out_b, xl, rbuf, Hq);
    gemv_kernel<<<dim3(Bq, Oq/4), 256, 0, stream>>>(fc_w, rbuf, fc_b, nullptr, outp, Oq);
}

// Round 6
// 923.459 us; speedup vs baseline: 1.1528x; 1.1528x over previous
//
#include <hip/hip_runtime.h>
#include <hip/hip_bf16.h>
#include <math.h>

// Problem constants (from reference setup_inputs)
#define Bq   16
#define Sq   1024
#define Hq   1024
#define Oq   256
#define Lq   4
#define NHq  8
#define DHq  128
#define Mq   (Bq*Sq)      // 16384 rows
#define HHq  (Hq*Hq)      // 1048576
#define NCc  32           // scan chunks
#define CTc  32           // timesteps per chunk

typedef __bf16 bf16x8 __attribute__((ext_vector_type(8)));
typedef float  f32x4  __attribute__((ext_vector_type(4)));

__device__ __forceinline__ float bf2f(unsigned int u) {
    union { unsigned int i; float f; } x; x.i = u << 16; return x.f;
}
__device__ __forceinline__ unsigned short f2bf(float f) {
    union { float f; unsigned int i; } x; x.f = f;
    unsigned int r = x.i + 0x7fffu + ((x.i >> 16) & 1u);   // RNE
    return (unsigned short)(r >> 16);
}
__device__ __forceinline__ float sigm(float x) { return 1.f / (1.f + __expf(-x)); }

__device__ __forceinline__ void gl2lds16(const unsigned short* g, unsigned short* l) {
    __builtin_amdgcn_global_load_lds((const __attribute__((address_space(1))) void*)g,
                                     (__attribute__((address_space(3))) void*)l, 16, 0, 0);
}

// ---------------- fp32 -> bf16 convert ----------------
__global__ void cvt_kernel(const float* __restrict__ src, unsigned short* __restrict__ dst, int n) {
    int i = blockIdx.x * 256 + threadIdx.x;
    if (i < n) dst[i] = f2bf(src[i]);
}

// ---------------- fused weight convert: Wcat[l][f;i;h][H][H] ----------------
__global__ void cvtW_kernel(const float* __restrict__ Wf, const float* __restrict__ Wi,
                            const float* __restrict__ Wh, unsigned short* __restrict__ Wcat) {
    int i = blockIdx.x * 256 + threadIdx.x;     // L*3*HH
    int l = (i >> 20) / 3;
    int r = i - l * 3 * HHq;
    int g = r >> 20; int j = r & (HHq - 1);
    const float* s = (g == 0) ? Wf : (g == 1) ? Wi : Wh;
    Wcat[i] = f2bf(s[(size_t)l * HHq + j]);
}

// ---------------- assemble per-layer [bf;bi;bh] bias (L x 3072) ----------------
__global__ void bias3_kernel(const float* __restrict__ bf_, const float* __restrict__ bi_,
                             const float* __restrict__ bh_, float* __restrict__ out) {
    int i = blockIdx.x * 256 + threadIdx.x;          // L*3H = 12288
    int l = i / (3*Hq); int r = i % (3*Hq); int g = r >> 10; int j = r & (Hq-1);
    const float* s = (g == 0) ? bf_ : (g == 1) ? bi_ : bh_;
    out[i] = s[l*Hq + j];
}

// ---------------- FUSED 3-gate GEMM + gate math ----------------
// Block = 128 timesteps x 64 channels x 3 gates. Stages A (128 rows) once per
// K-iter and W f/i/h (3x64 rows): 96 MFMA per 320 staged rows (1.5x intensity
// of the plain GEMM). acc = 3x4x2 f32x4 = 96 AGPR; launch_bounds(256,3) keeps
// 3 waves/SIMD -> 3 blocks/CU (LDS 40KB dbuf also allows it).
// Epilogue computes f,i sigmoid + fp=f/(f+i), add=i/(f+i)*ht and writes FP/ADD
// bf16 directly (Gpre buffer + separate gate pass eliminated).
// Swizzle identical to R2's verified zero-conflict mapping.
__global__ __launch_bounds__(256, 3)
void gemm_gate_kernel(const unsigned short* __restrict__ A, const unsigned short* __restrict__ Wl,
                      const float* __restrict__ bias3, unsigned short* __restrict__ FPo,
                      unsigned short* __restrict__ ADDo)
{
    const int K = Hq;
    __shared__ unsigned short As[2*4096];     //  16 KB: 2 x 128 rows x 32
    __shared__ unsigned short Ws[2*6144];     //  24 KB: 2 x 192 rows x 32 (f,i,h stacked 64 each)
    const int tid  = threadIdx.x;

    // XCD swizzle: 128 bm-rows total, 16 per XCD; cb (16) fastest -> A-tile shared
    // by 16 consecutive blocks on one XCD.
    const int lid = blockIdx.x;               // 2048 blocks
    const int xcd = lid & 7;
    const int s   = lid >> 3;                 // 0..255
    const int bm  = xcd * 16 + (s >> 4);
    const int cb  = s & 15;                   // channel block (64 channels)

    const int wid  = tid >> 6, lane = tid & 63;
    const int wm   = (wid >> 1) * 64;         // 0/64
    const int wn   = (wid & 1) * 32;          // 0/32
    const int l15  = lane & 15, quad = lane >> 4;

    const unsigned short* Ag = A + (size_t)(bm*128) * K;

    // --- staging offsets (R2 swizzle: key=(lane>>3)&3, phys chunk lane&3) ---
    const int lr   = lane >> 2;               // 0..15 row within 16-row issue
    const int gc   = (lane & 3) ^ ((lane >> 3) & 3);
    // A: wave w stages rows [w*32, w*32+32) in 2 issues of 16 rows
    size_t offA[2]; int ldsA[2];
    #pragma unroll
    for (int q = 0; q < 2; ++q) {
        int ra = wid*32 + q*16 + lr;
        offA[q] = (size_t)ra * K + gc*8;
        ldsA[q] = (wid*32 + q*16) * 32;
    }
    // W: wave w stages LDS rows [w*48, w*48+48) in 3 issues of 16 rows.
    // LDS row rw -> gate g=rw>>6, row-in-gate nr=rw&63 (issues never cross gates).
    size_t offW[3]; int ldsW[3];
    #pragma unroll
    for (int q = 0; q < 3; ++q) {
        int rw = wid*48 + q*16 + lr;
        int g  = rw >> 6;
        int nr = rw & 63;
        offW[q] = (size_t)g * HHq + (size_t)(cb*64 + nr) * K + gc*8;
        ldsW[q] = (wid*48 + q*16) * 32;
    }

    // fragment read swizzle: phys chunk = quad ^ ((l15>>1)&3)
    const int crd = quad ^ ((l15 >> 1) & 3);

    f32x4 acc[3][4][2] = {};

    const int niter = K >> 5;                 // 32

    // prologue: stage buf0
    #pragma unroll
    for (int q = 0; q < 2; ++q) gl2lds16(Ag + offA[q], &As[ldsA[q]]);
    #pragma unroll
    for (int q = 0; q < 3; ++q) gl2lds16(Wl + offW[q], &Ws[ldsW[q]]);
    __syncthreads();

    for (int it = 0; it < niter; ++it) {
        const int cur = it & 1;
        if (it + 1 < niter) {
            const int nxt = (it + 1) & 1;
            const size_t k1 = (size_t)(it + 1) << 5;
            #pragma unroll
            for (int q = 0; q < 2; ++q) gl2lds16(Ag + offA[q] + k1, &As[nxt*4096 + ldsA[q]]);
            #pragma unroll
            for (int q = 0; q < 3; ++q) gl2lds16(Wl + offW[q] + k1, &Ws[nxt*6144 + ldsW[q]]);
        }
        bf16x8 af[4];
        #pragma unroll
        for (int t = 0; t < 4; ++t)
            af[t] = *(const bf16x8*)&As[cur*4096 + (wm + t*16 + l15)*32 + crd*8];
        #pragma unroll
        for (int g = 0; g < 3; ++g) {
            bf16x8 wf[2];
            #pragma unroll
            for (int t = 0; t < 2; ++t)
                wf[t] = *(const bf16x8*)&Ws[cur*6144 + (g*64 + wn + t*16 + l15)*32 + crd*8];
            #pragma unroll
            for (int tm = 0; tm < 4; ++tm)
                #pragma unroll
                for (int tn = 0; tn < 2; ++tn)
                    acc[g][tm][tn] = __builtin_amdgcn_mfma_f32_16x16x32_bf16(af[tm], wf[tn], acc[g][tm][tn], 0, 0, 0);
        }
        __syncthreads();
    }

    // epilogue: gate math + bf16 FP/ADD write (C layout: row=quad*4+r, col=l15)
    #pragma unroll
    for (int tm = 0; tm < 4; ++tm) {
        int row0 = bm*128 + wm + tm*16 + quad*4;
        #pragma unroll
        for (int tn = 0; tn < 2; ++tn) {
            int col = cb*64 + wn + tn*16 + l15;
            float bf_ = bias3[col], bi_ = bias3[Hq + col], bh_ = bias3[2*Hq + col];
            #pragma unroll
            for (int r = 0; r < 4; ++r) {
                float f  = sigm(acc[0][tm][tn][r] + bf_);
                float i  = sigm(acc[1][tm][tn][r] + bi_);
                float ht = acc[2][tm][tn][r] + bh_;
                float rd = 1.f / (f + i);
                size_t off = (size_t)(row0 + r) * Hq + col;
                FPo[off]  = f2bf(f * rd);
                ADDo[off] = f2bf(i * rd * ht);
            }
        }
    }
}

// ---------------- plain bf16 GEMM (used for KV projection) ----------------
// R5 structure: 128x128 tile, BK=32, dbuf LDS, one barrier/iter, XCD swizzle.
__global__ __launch_bounds__(256)
void gemm_bt_kernel(const unsigned short* __restrict__ A, const unsigned short* __restrict__ W,
                    const float* __restrict__ bias, unsigned short* __restrict__ C,
                    int N, int K, int nbn)
{
    __shared__ unsigned short As[2*4096];
    __shared__ unsigned short Ws[2*4096];
    const int tid  = threadIdx.x;

    const int lid = blockIdx.x;
    const int xcd = lid & 7;
    const int s   = lid >> 3;
    const int bm  = xcd * 16 + s / nbn;
    const int bn  = s % nbn;

    const int wid  = tid >> 6, lane = tid & 63;
    const int wm   = (wid >> 1) * 64, wn = (wid & 1) * 64;
    const int l15  = lane & 15, quad = lane >> 4;

    const unsigned short* Ag = A + (size_t)(bm*128) * K;
    const unsigned short* Wg = W + (size_t)(bn*128) * K;

    const int r0   = wid*32 + (lane >> 2);
    const int cst  = (lane & 3) ^ ((r0 >> 1) & 3);
    const size_t g0 = (size_t)r0 * K + cst*8;
    const size_t g1 = (size_t)(r0 + 16) * K + cst*8;
    const int lofs0 = wid*1024;
    const int lofs1 = wid*1024 + 512;

    const int crd = quad ^ ((l15 >> 1) & 3);

    f32x4 acc[4][4] = {};

    const int niter = K >> 5;

    gl2lds16(Ag + g0, &As[lofs0]);
    gl2lds16(Ag + g1, &As[lofs1]);
    gl2lds16(Wg + g0, &Ws[lofs0]);
    gl2lds16(Wg + g1, &Ws[lofs1]);
    __syncthreads();

    for (int it = 0; it < niter; ++it) {
        const int cur = it & 1;
        if (it + 1 < niter) {
            const int nxt = (it + 1) & 1;
            const size_t k1 = (size_t)(it + 1) << 5;
            gl2lds16(Ag + g0 + k1, &As[nxt*4096 + lofs0]);
            gl2lds16(Ag + g1 + k1, &As[nxt*4096 + lofs1]);
            gl2lds16(Wg + g0 + k1, &Ws[nxt*4096 + lofs0]);
            gl2lds16(Wg + g1 + k1, &Ws[nxt*4096 + lofs1]);
        }
        bf16x8 af[4], wf[4];
        #pragma unroll
        for (int t = 0; t < 4; ++t) {
            af[t] = *(const bf16x8*)&As[cur*4096 + (wm + t*16 + l15)*32 + crd*8];
            wf[t] = *(const bf16x8*)&Ws[cur*4096 + (wn + t*16 + l15)*32 + crd*8];
        }
        #pragma unroll
        for (int tm = 0; tm < 4; ++tm)
            #pragma unroll
            for (int tn = 0; tn < 4; ++tn)
                acc[tm][tn] = __builtin_amdgcn_mfma_f32_16x16x32_bf16(af[tm], wf[tn], acc[tm][tn], 0, 0, 0);
        __syncthreads();
    }

    #pragma unroll
    for (int tm = 0; tm < 4; ++tm) {
        int row0 = bm*128 + wm + tm*16 + quad*4;
        #pragma unroll
        for (int tn = 0; tn < 4; ++tn) {
            int col = bn*128 + wn + tn*16 + l15;
            float bv = bias[col];
            #pragma unroll
            for (int r = 0; r < 4; ++r)
                C[(size_t)(row0 + r) * N + col] = f2bf(acc[tm][tn][r] + bv);
        }
    }
}

// ---------------- chunked scan over precomputed FP/ADD ----------------
// Pass A: per (b,chunk,j-pair): P = prod fp, Asum = local scan from h=0.
__global__ __launch_bounds__(256)
void scan_sum_kernel(const unsigned short* __restrict__ FP, const unsigned short* __restrict__ AD,
                     float* __restrict__ Ps, float* __restrict__ Asum) {
    int bid = blockIdx.x;                    // B*NC*2 = 1024
    int tid = threadIdx.x;
    int b = bid >> 6; int r = bid & 63; int chunk = r >> 1; int jb = r & 1;
    int j = jb*512 + tid*2;
    size_t base = ((size_t)(b*Sq + chunk*CTc)) * Hq + j;
    float P0 = 1.f, P1 = 1.f, A0 = 0.f, A1 = 0.f;
    for (int s = 0; s < CTc; ++s) {
        size_t ro = base + (size_t)s * Hq;
        unsigned int uf = *(const unsigned int*)(FP + ro);
        unsigned int ua = *(const unsigned int*)(AD + ro);
        float fp0 = bf2f(uf & 0xffffu), fp1 = bf2f(uf >> 16);
        float ad0 = bf2f(ua & 0xffffu), ad1 = bf2f(ua >> 16);
        P0 *= fp0; A0 = fp0 * A0 + ad0;
        P1 *= fp1; A1 = fp1 * A1 + ad1;
    }
    int oi = (b*NCc + chunk)*Hq + j;
    Ps[oi] = P0; Ps[oi+1] = P1;
    Asum[oi] = A0; Asum[oi+1] = A1;
}

// Pass B: chunk-level prefix. h entering chunk c stored to Hb.
__global__ void scan_base_kernel(const float* __restrict__ Ps, const float* __restrict__ Asum,
                                 float* __restrict__ Hb) {
    int t = blockIdx.x * 256 + threadIdx.x;  // B*H = 16384
    int b = t >> 10, j = t & 1023;
    float h = 0.f;
    for (int c = 0; c < NCc; ++c) {
        int idx = (b*NCc + c)*Hq + j;
        Hb[idx] = h;
        h = Ps[idx] * h + Asum[idx];
    }
}

// Pass C: re-read FP/ADD, scan with correct init, write bf16 h.
__global__ __launch_bounds__(256)
void scan_out_kernel(const unsigned short* __restrict__ FP, const unsigned short* __restrict__ AD,
                     const float* __restrict__ Hb, unsigned short* __restrict__ Ho) {
    int bid = blockIdx.x;                    // B*NC*2 = 1024
    int tid = threadIdx.x;
    int b = bid >> 6; int r = bid & 63; int chunk = r >> 1; int jb = r & 1;
    int j = jb*512 + tid*2;
    size_t base = ((size_t)(b*Sq + chunk*CTc)) * Hq + j;
    int oi = (b*NCc + chunk)*Hq + j;
    float h0 = Hb[oi], h1 = Hb[oi+1];
    for (int s = 0; s < CTc; ++s) {
        size_t ro = base + (size_t)s * Hq;
        unsigned int uf = *(const unsigned int*)(FP + ro);
        unsigned int ua = *(const unsigned int*)(AD + ro);
        h0 = bf2f(uf & 0xffffu) * h0 + bf2f(ua & 0xffffu);
        h1 = bf2f(uf >> 16)     * h1 + bf2f(ua >> 16);
        unsigned int packed = (unsigned int)f2bf(h0) | ((unsigned int)f2bf(h1) << 16);
        *(unsigned int*)(Ho + ro) = packed;
    }
}

// ---------------- extract last-position activations as fp32 ----------------
__global__ void xlast_kernel(const unsigned short* __restrict__ act, float* __restrict__ xl) {
    int i = blockIdx.x * 256 + threadIdx.x;  // B*H
    int b = i >> 10, j = i & 1023;
    xl[i] = bf2f((unsigned int)act[((size_t)(b*Sq + Sq-1)) * Hq + j]);
}

// ---------------- wave-per-row GEMV: out[b,n] = W[n,:].x[b,:] + bias[n] (+resid[b,n]) ----------------
__global__ __launch_bounds__(256)
void gemv_kernel(const float* __restrict__ W, const float* __restrict__ xv,
                 const float* __restrict__ bias, const float* __restrict__ resid,
                 float* __restrict__ out, int N) {
    int b = blockIdx.x;
    int w = threadIdx.x >> 6, lane = threadIdx.x & 63;
    int n = blockIdx.y*4 + w;
    __shared__ float xs[Hq];
    *(float4*)&xs[threadIdx.x*4] = *(const float4*)&xv[(size_t)b*Hq + threadIdx.x*4];
    __syncthreads();
    const float4* wr = (const float4*)(W + (size_t)n * Hq);
    float a = 0.f;
    #pragma unroll
    for (int c = 0; c < 4; ++c) {
        float4 wv = wr[c*64 + lane];
        float4 x4 = *(const float4*)&xs[c*256 + lane*4];
        a += wv.x*x4.x + wv.y*x4.y + wv.z*x4.z + wv.w*x4.w;
    }
    #pragma unroll
    for (int st = 32; st > 0; st >>= 1) a += __shfl_xor(a, st, 64);
    if (lane == 0) out[(size_t)b*N + n] = a + bias[n] + (resid ? resid[(size_t)b*Hq + n] : 0.f);
}

// ---------------- attention for the single last-position query ----------------
__global__ __launch_bounds__(1024)
void attn_kernel(const unsigned short* __restrict__ KV,
                 const float* __restrict__ q, float* __restrict__ o) {
    int b = blockIdx.x >> 3, nh = blockIdx.x & 7;
    int tid = threadIdx.x;
    __shared__ float qs[DHq];
    __shared__ float p[Sq];
    __shared__ float redw[16];
    __shared__ float red2[16*DHq];
    if (tid < DHq) qs[tid] = q[b*Hq + nh*DHq + tid] * 0.08838834764831845f;
    __syncthreads();

    const int g = tid >> 4, l = tid & 15;
    const unsigned short* Kb = KV + (size_t)b*Sq*2048 + nh*DHq;
    float lmax = -1e30f;
    #pragma unroll 4
    for (int it = 0; it < 16; ++it) {
        int s = it*64 + g;
        union { uint4 v; unsigned short u[8]; } kk;
        kk.v = *(const uint4*)(Kb + (size_t)s*2048 + l*8);
        float a = 0.f;
        #pragma unroll
        for (int j = 0; j < 8; ++j) a += bf2f((unsigned int)kk.u[j]) * qs[l*8 + j];
        a += __shfl_xor(a, 1, 16);
        a += __shfl_xor(a, 2, 16);
        a += __shfl_xor(a, 4, 16);
        a += __shfl_xor(a, 8, 16);
        if (l == 0) p[s] = a;
        lmax = fmaxf(lmax, a);
    }
    #pragma unroll
    for (int st = 32; st > 0; st >>= 1) lmax = fmaxf(lmax, __shfl_xor(lmax, st, 64));
    if ((tid & 63) == 0) redw[tid >> 6] = lmax;
    __syncthreads();
    float mx = redw[0];
    #pragma unroll
    for (int i = 1; i < 16; ++i) mx = fmaxf(mx, redw[i]);

    float e = __expf(p[tid] - mx);
    float ls = e;
    #pragma unroll
    for (int st = 32; st > 0; st >>= 1) ls += __shfl_xor(ls, st, 64);
    __syncthreads();
    p[tid] = e;
    if ((tid & 63) == 0) redw[tid >> 6] = ls;
    __syncthreads();
    float ssum = 0.f;
    #pragma unroll
    for (int i = 0; i < 16; ++i) ssum += redw[i];
    float inv = 1.f / ssum;

    int d2 = (tid & 63) * 2, sb = tid >> 6;
    const unsigned short* Vb = KV + (size_t)b*Sq*2048 + 1024 + nh*DHq + d2;
    float a0 = 0.f, a1 = 0.f;
    for (int s = sb*64; s < sb*64 + 64; ++s) {
        unsigned int vv = *(const unsigned int*)(Vb + (size_t)s*2048);
        float pw = p[s];
        a0 += pw * bf2f(vv & 0xffffu);
        a1 += pw * bf2f(vv >> 16);
    }
    red2[sb*DHq + d2] = a0;
    red2[sb*DHq + d2 + 1] = a1;
    __syncthreads();
    if (tid < DHq) {
        float a = 0.f;
        #pragma unroll
        for (int i = 0; i < 16; ++i) a += red2[i*DHq + tid];
        o[b*Hq + nh*DHq + tid] = a * inv;
    }
}

extern "C" void kernel_launch(void* const* d_in, const int* in_sizes, int n_in,
                              void* d_out, int out_size, void* d_ws, size_t ws_size,
                              hipStream_t stream) {
    const float* x        = (const float*)d_in[0];
    const float* Wf       = (const float*)d_in[1];
    const float* bfv      = (const float*)d_in[2];
    const float* Wi       = (const float*)d_in[3];
    const float* biv      = (const float*)d_in[4];
    const float* Wh       = (const float*)d_in[5];
    const float* bhv      = (const float*)d_in[6];
    const float* in_proj_w= (const float*)d_in[7];
    const float* in_proj_b= (const float*)d_in[8];
    const float* out_w    = (const float*)d_in[9];
    const float* out_b    = (const float*)d_in[10];
    const float* fc_w     = (const float*)d_in[11];
    const float* fc_b     = (const float*)d_in[12];
    float* outp = (float*)d_out;

    // workspace carve (~160 MB)
    char* p = (char*)d_ws;
    auto alloc = [&](size_t bytes) -> void* {
        void* r = (void*)p; p += (bytes + 255) & ~(size_t)255; return r;
    };
    unsigned short* Wcat = (unsigned short*)alloc((size_t)Lq*3*HHq*2);  // 24 MB
    unsigned short* Wkv  = (unsigned short*)alloc((size_t)2048*Hq*2);   //  4 MB
    float*          Bias3= (float*)alloc((size_t)Lq*3*Hq*4);            // 48 KB
    unsigned short* actA = (unsigned short*)alloc((size_t)Mq*Hq*2);     // 32 MB
    unsigned short* actB = (unsigned short*)alloc((size_t)Mq*Hq*2);     // 32 MB
    unsigned short* FPg  = (unsigned short*)alloc((size_t)Mq*Hq*2);     // 32 MB
    unsigned short* ADDg = (unsigned short*)alloc((size_t)Mq*Hq*2);     // 32 MB (contiguous after FPg)
    float* Ps   = (float*)alloc((size_t)Bq*NCc*Hq*4);                   //  2 MB
    float* Asum = (float*)alloc((size_t)Bq*NCc*Hq*4);                   //  2 MB
    float* Hb   = (float*)alloc((size_t)Bq*NCc*Hq*4);                   //  2 MB
    unsigned short* KV = FPg;  // alias: 64 MB (FPg+ADDg), used only after layers done
    float* xl   = (float*)alloc((size_t)Bq*Hq*4);
    float* qbuf = (float*)alloc((size_t)Bq*Hq*4);
    float* obuf = (float*)alloc((size_t)Bq*Hq*4);
    float* rbuf = (float*)alloc((size_t)Bq*Hq*4);

    // --- conversions ---
    cvt_kernel<<<Mq*Hq/256, 256, 0, stream>>>(x, actA, Mq*Hq);
    cvtW_kernel<<<Lq*3*HHq/256, 256, 0, stream>>>(Wf, Wi, Wh, Wcat);
    cvt_kernel<<<2048*Hq/256, 256, 0, stream>>>(in_proj_w + (size_t)Hq*Hq, Wkv, 2048*Hq);
    bias3_kernel<<<(Lq*3*Hq)/256, 256, 0, stream>>>(bfv, biv, bhv, Bias3);

    // --- minLSTM layers ---
    unsigned short* cur = actA;
    unsigned short* nxt = actB;
    for (int l = 0; l < Lq; ++l) {
        gemm_gate_kernel<<<(Mq/128)*16, 256, 0, stream>>>(
            cur, Wcat + (size_t)l*3*HHq, Bias3 + l*3*Hq, FPg, ADDg);
        scan_sum_kernel<<<Bq*NCc*2, 256, 0, stream>>>(FPg, ADDg, Ps, Asum);
        scan_base_kernel<<<Bq*Hq/256, 256, 0, stream>>>(Ps, Asum, Hb);
        scan_out_kernel<<<Bq*NCc*2, 256, 0, stream>>>(FPg, ADDg, Hb, nxt);
        unsigned short* t = cur; cur = nxt; nxt = t;
    }

    // --- attention (only last-position query matters) ---
    gemm_bt_kernel<<<(Mq/128)*(2048/128), 256, 0, stream>>>(
        cur, Wkv, in_proj_b + Hq, KV, 2048, Hq, 2048/128);
    xlast_kernel<<<Bq*Hq/256, 256, 0, stream>>>(cur, xl);
    gemv_kernel<<<dim3(Bq, Hq/4), 256, 0, stream>>>(in_proj_w, xl, in_proj_b, nullptr, qbuf, Hq);
    attn_kernel<<<Bq*NHq, 1024, 0, stream>>>(KV, qbuf, obuf);
    gemv_kernel<<<dim3(Bq, Hq/4), 256, 0, stream>>>(out_w, obuf, out_b, xl, rbuf, Hq);
    gemv_kernel<<<dim3(Bq, Oq/4), 256, 0, stream>>>(fc_w, rbuf, fc_b, nullptr, outp, Oq);
}